// Round 3
// baseline (687.102 us; speedup 1.0000x reference)
//
#include <hip/hip_runtime.h>

// Problem constants:
//   x: [4096,1] f32, edge_index: [2,131072] int32 on device, W1: [1,8] f32,
//   b1: [8] f32, Wr: [32768,4096] f32 (512 MB -- the whole cost), br: [4096] f32
//   out: [4096] f32
// Structure exploit: xw[i,j] = x[i]*W1[j] (rank-1), so GCN aggregation is a
// SCALAR scatter; relu kills ~50% of h entries and each zero h[k] skips a
// 16 KB row of Wr -> compact nonzeros once, stream only live rows.
#define N_NODES 4096
#define HID 8
#define N_EDGES 131072
#define YDIM 4096
#define K_TOT (N_NODES * HID)   // 32768
#define NCHUNK 256              // k-slices of the nz list
#define GEMV_BLOCK 256

// ---- K1: init deg (self-loop = 1), t accumulator, out = br, nnz = 0 ----
__global__ __launch_bounds__(256) void k_init(float* __restrict__ deg,
                                              float* __restrict__ t,
                                              float* __restrict__ out,
                                              const float* __restrict__ br,
                                              int* __restrict__ nnz) {
  int i = blockIdx.x * blockDim.x + threadIdx.x;
  if (i < N_NODES) { deg[i] = 1.0f; t[i] = 0.0f; out[i] = br[i]; }
  if (i == 0) *nnz = 0;
}

// ---- K2: degree count over dst ----
__global__ __launch_bounds__(256) void k_deg(const int* __restrict__ ei,
                                             float* __restrict__ deg) {
  int e = blockIdx.x * blockDim.x + threadIdx.x;
  if (e < N_EDGES) atomicAdd(&deg[ei[N_EDGES + e]], 1.0f);
}

// ---- K3: dinv = rsqrt(deg) ----
__global__ __launch_bounds__(256) void k_dinv(const float* __restrict__ deg,
                                              float* __restrict__ dinv) {
  int i = blockIdx.x * blockDim.x + threadIdx.x;
  if (i < N_NODES) dinv[i] = rsqrtf(deg[i]);
}

// ---- K4: t[dst] += x[src]*dinv[src] ----
__global__ __launch_bounds__(256) void k_scatter(const int* __restrict__ ei,
                                                 const float* __restrict__ x,
                                                 const float* __restrict__ dinv,
                                                 float* __restrict__ t) {
  int e = blockIdx.x * blockDim.x + threadIdx.x;
  if (e < N_EDGES) {
    int s = ei[e];
    int d = ei[N_EDGES + e];
    atomicAdd(&t[d], x[s] * dinv[s]);
  }
}

// ---- K5: h[i*8+j] = relu(dinv[i]*(t[i]+x[i]*dinv[i])*W1[j] + b1[j]),
//          compacted globally into (nzk = k*YDIM, nzv = h) ----
__global__ __launch_bounds__(256) void k_hc(const float* __restrict__ x,
                                            const float* __restrict__ dinv,
                                            const float* __restrict__ t,
                                            const float* __restrict__ W1,
                                            const float* __restrict__ b1,
                                            int* __restrict__ nnz,
                                            int* __restrict__ nzk,
                                            float* __restrict__ nzv) {
  int i = blockIdx.x * blockDim.x + threadIdx.x;
  if (i >= N_NODES) return;
  float di = dinv[i];
  float s = di * (t[i] + x[i] * di);
  float v[HID];
  int nloc = 0;
#pragma unroll
  for (int j = 0; j < HID; ++j) {
    float u = s * W1[j] + b1[j];
    v[j] = u;
    nloc += (u > 0.0f) ? 1 : 0;
  }
  int p = atomicAdd(nnz, nloc);
#pragma unroll
  for (int j = 0; j < HID; ++j) {
    if (v[j] > 0.0f) {
      nzk[p] = (i * HID + j) * YDIM;  // pre-scaled row offset
      nzv[p] = v[j];
      ++p;
    }
  }
}

// ---- K6: split-K GEMV over the compacted nz list ----
// grid = 4 column-groups x NCHUNK nz-slices. Unroll-by-4 with 4 independent
// accumulator sets -> 4 outstanding 1KB loads per wave (latency hiding).
__global__ __launch_bounds__(GEMV_BLOCK) void k_gemv(const float* __restrict__ Wr,
                                                     const int* __restrict__ nnzp,
                                                     const int* __restrict__ nzk,
                                                     const float* __restrict__ nzv,
                                                     float* __restrict__ out) {
  __shared__ float hs[160];   // slice <= ceil(32768/256) = 128
  __shared__ int ks[160];
  const int tid = threadIdx.x;
  const int cg = blockIdx.x & 3;    // column group (4 x 1024 cols)
  const int ck = blockIdx.x >> 2;   // nz-slice index
  const int nnz = *nnzp;
  const int qs = (ck * nnz) >> 8;         // NCHUNK = 256
  const int qe = ((ck + 1) * nnz) >> 8;
  const int cnt = qe - qs;
  if (tid < cnt) { hs[tid] = nzv[qs + tid]; ks[tid] = nzk[qs + tid]; }
  __syncthreads();

  const int col = cg * (GEMV_BLOCK * 4) + tid * 4;
  const float* base = Wr + col;
  float4 a0 = {0, 0, 0, 0}, a1 = {0, 0, 0, 0}, a2 = {0, 0, 0, 0}, a3 = {0, 0, 0, 0};
  int q = 0;
  for (; q + 4 <= cnt; q += 4) {
    float h0 = hs[q], h1 = hs[q + 1], h2 = hs[q + 2], h3 = hs[q + 3];
    const float4 w0 = *(const float4*)(base + (size_t)(unsigned)ks[q]);
    const float4 w1 = *(const float4*)(base + (size_t)(unsigned)ks[q + 1]);
    const float4 w2 = *(const float4*)(base + (size_t)(unsigned)ks[q + 2]);
    const float4 w3 = *(const float4*)(base + (size_t)(unsigned)ks[q + 3]);
    a0.x += h0 * w0.x; a0.y += h0 * w0.y; a0.z += h0 * w0.z; a0.w += h0 * w0.w;
    a1.x += h1 * w1.x; a1.y += h1 * w1.y; a1.z += h1 * w1.z; a1.w += h1 * w1.w;
    a2.x += h2 * w2.x; a2.y += h2 * w2.y; a2.z += h2 * w2.z; a2.w += h2 * w2.w;
    a3.x += h3 * w3.x; a3.y += h3 * w3.y; a3.z += h3 * w3.z; a3.w += h3 * w3.w;
  }
  for (; q < cnt; ++q) {
    float h0 = hs[q];
    const float4 w0 = *(const float4*)(base + (size_t)(unsigned)ks[q]);
    a0.x += h0 * w0.x; a0.y += h0 * w0.y; a0.z += h0 * w0.z; a0.w += h0 * w0.w;
  }
  float rx = a0.x + a1.x + a2.x + a3.x;
  float ry = a0.y + a1.y + a2.y + a3.y;
  float rz = a0.z + a1.z + a2.z + a3.z;
  float rw = a0.w + a1.w + a2.w + a3.w;
  atomicAdd(&out[col + 0], rx);
  atomicAdd(&out[col + 1], ry);
  atomicAdd(&out[col + 2], rz);
  atomicAdd(&out[col + 3], rw);
}

extern "C" void kernel_launch(void* const* d_in, const int* in_sizes, int n_in,
                              void* d_out, int out_size, void* d_ws, size_t ws_size,
                              hipStream_t stream) {
  const float* x  = (const float*)d_in[0];
  const int*   ei = (const int*)d_in[1];
  const float* W1 = (const float*)d_in[2];
  const float* b1 = (const float*)d_in[3];
  const float* Wr = (const float*)d_in[4];
  const float* br = (const float*)d_in[5];
  float* out = (float*)d_out;

  // ws layout (fp32/int32): deg[4096] dinv[4096] t[4096] nnz[16] nzk[32768] nzv[32768]
  float* deg  = (float*)d_ws;
  float* dinv = deg + N_NODES;
  float* t    = dinv + N_NODES;
  int*   nnz  = (int*)(t + N_NODES);
  int*   nzk  = nnz + 16;
  float* nzv  = (float*)(nzk + K_TOT);

  k_init   <<<(N_NODES + 255) / 256, 256, 0, stream>>>(deg, t, out, br, nnz);
  k_deg    <<<(N_EDGES + 255) / 256, 256, 0, stream>>>(ei, deg);
  k_dinv   <<<(N_NODES + 255) / 256, 256, 0, stream>>>(deg, dinv);
  k_scatter<<<(N_EDGES + 255) / 256, 256, 0, stream>>>(ei, x, dinv, t);
  k_hc     <<<(N_NODES + 255) / 256, 256, 0, stream>>>(x, dinv, t, W1, b1, nnz, nzk, nzv);
  k_gemv   <<<4 * NCHUNK, GEMV_BLOCK, 0, stream>>>(Wr, nnz, nzk, nzv, out);
}

// Round 4
// 681.884 us; speedup vs baseline: 1.0077x; 1.0077x over previous
//
#include <hip/hip_runtime.h>

// Problem constants:
//   x: [4096,1] f32, edge_index: [2,131072] int32 on device, W1: [1,8] f32,
//   b1: [8] f32, Wr: [32768,4096] f32 (512 MB -- the whole cost), br: [4096] f32
//   out: [4096] f32
// Structure exploits:
//   - xw[i,j] = x[i]*W1[j] (rank-1) -> GCN aggregation is a SCALAR scatter.
//   - relu kills ~50% of h entries; each zero h[k] skips a 16 KB row of Wr.
//     Compact nonzeros once globally, stream only live rows (~268 MB @ 6.3 TB/s
//     ~= 43 us -- the structural HBM floor for the readout GEMV).
#define N_NODES 4096
#define HID 8
#define N_EDGES 131072
#define YDIM 4096
#define K_TOT (N_NODES * HID)   // 32768
#define NCHUNK 256              // k-slices of the nz list
#define GEMV_BLOCK 256

// ---- K1: init deg (self-loop = 1), t accumulator, out = br, nnz = 0 ----
__global__ __launch_bounds__(256) void k_init(float* __restrict__ deg,
                                              float* __restrict__ t,
                                              float* __restrict__ out,
                                              const float* __restrict__ br,
                                              int* __restrict__ nnz) {
  int i = blockIdx.x * blockDim.x + threadIdx.x;
  if (i < N_NODES) { deg[i] = 1.0f; t[i] = 0.0f; out[i] = br[i]; }
  if (i == 0) *nnz = 0;
}

// ---- K2: degree count over dst ----
__global__ __launch_bounds__(256) void k_deg(const int* __restrict__ ei,
                                             float* __restrict__ deg) {
  int e = blockIdx.x * blockDim.x + threadIdx.x;
  if (e < N_EDGES) atomicAdd(&deg[ei[N_EDGES + e]], 1.0f);
}

// ---- K3: t[dst] += x[src]*rsqrt(deg[src])  (dinv computed on the fly) ----
__global__ __launch_bounds__(256) void k_scatter(const int* __restrict__ ei,
                                                 const float* __restrict__ x,
                                                 const float* __restrict__ deg,
                                                 float* __restrict__ t) {
  int e = blockIdx.x * blockDim.x + threadIdx.x;
  if (e < N_EDGES) {
    int s = ei[e];
    int d = ei[N_EDGES + e];
    atomicAdd(&t[d], x[s] * rsqrtf(deg[s]));
  }
}

// ---- K4: h[i*8+j] = relu(dinv_i*(t[i]+x[i]*dinv_i)*W1[j] + b1[j]),
//          compacted globally into (nzk = k*YDIM, nzv = h) ----
__global__ __launch_bounds__(256) void k_hc(const float* __restrict__ x,
                                            const float* __restrict__ deg,
                                            const float* __restrict__ t,
                                            const float* __restrict__ W1,
                                            const float* __restrict__ b1,
                                            int* __restrict__ nnz,
                                            int* __restrict__ nzk,
                                            float* __restrict__ nzv) {
  int i = blockIdx.x * blockDim.x + threadIdx.x;
  if (i >= N_NODES) return;
  float di = rsqrtf(deg[i]);
  float s = di * (t[i] + x[i] * di);
  float v[HID];
  int nloc = 0;
#pragma unroll
  for (int j = 0; j < HID; ++j) {
    float u = s * W1[j] + b1[j];
    v[j] = u;
    nloc += (u > 0.0f) ? 1 : 0;
  }
  int p = atomicAdd(nnz, nloc);
#pragma unroll
  for (int j = 0; j < HID; ++j) {
    if (v[j] > 0.0f) {
      nzk[p] = (i * HID + j) * YDIM;  // pre-scaled row offset
      nzv[p] = v[j];
      ++p;
    }
  }
}

// ---- K5: split-K GEMV over the compacted nz list ----
// grid = 4 column-groups x NCHUNK nz-slices (1024 blocks = 4/CU, 16 waves/CU).
// Unroll-by-4 with independent accumulator sets -> 4 outstanding 1KB loads per
// wave; 64 KB in flight per CU >> Little's-law requirement for 6.3 TB/s.
__global__ __launch_bounds__(GEMV_BLOCK) void k_gemv(const float* __restrict__ Wr,
                                                     const int* __restrict__ nnzp,
                                                     const int* __restrict__ nzk,
                                                     const float* __restrict__ nzv,
                                                     float* __restrict__ out) {
  __shared__ float hs[160];   // slice <= ceil(32768/256) = 128
  __shared__ int ks[160];
  const int tid = threadIdx.x;
  const int cg = blockIdx.x & 3;    // column group (4 x 1024 cols)
  const int ck = blockIdx.x >> 2;   // nz-slice index
  const int nnz = *nnzp;
  const int qs = (ck * nnz) >> 8;         // NCHUNK = 256
  const int qe = ((ck + 1) * nnz) >> 8;
  const int cnt = qe - qs;
  if (tid < cnt) { hs[tid] = nzv[qs + tid]; ks[tid] = nzk[qs + tid]; }
  __syncthreads();

  const int col = cg * (GEMV_BLOCK * 4) + tid * 4;
  const float* base = Wr + col;
  float4 a0 = {0, 0, 0, 0}, a1 = {0, 0, 0, 0}, a2 = {0, 0, 0, 0}, a3 = {0, 0, 0, 0};
  int q = 0;
  for (; q + 4 <= cnt; q += 4) {
    float h0 = hs[q], h1 = hs[q + 1], h2 = hs[q + 2], h3 = hs[q + 3];
    const float4 w0 = *(const float4*)(base + (size_t)(unsigned)ks[q]);
    const float4 w1 = *(const float4*)(base + (size_t)(unsigned)ks[q + 1]);
    const float4 w2 = *(const float4*)(base + (size_t)(unsigned)ks[q + 2]);
    const float4 w3 = *(const float4*)(base + (size_t)(unsigned)ks[q + 3]);
    a0.x += h0 * w0.x; a0.y += h0 * w0.y; a0.z += h0 * w0.z; a0.w += h0 * w0.w;
    a1.x += h1 * w1.x; a1.y += h1 * w1.y; a1.z += h1 * w1.z; a1.w += h1 * w1.w;
    a2.x += h2 * w2.x; a2.y += h2 * w2.y; a2.z += h2 * w2.z; a2.w += h2 * w2.w;
    a3.x += h3 * w3.x; a3.y += h3 * w3.y; a3.z += h3 * w3.z; a3.w += h3 * w3.w;
  }
  for (; q < cnt; ++q) {
    float h0 = hs[q];
    const float4 w0 = *(const float4*)(base + (size_t)(unsigned)ks[q]);
    a0.x += h0 * w0.x; a0.y += h0 * w0.y; a0.z += h0 * w0.z; a0.w += h0 * w0.w;
  }
  float rx = a0.x + a1.x + a2.x + a3.x;
  float ry = a0.y + a1.y + a2.y + a3.y;
  float rz = a0.z + a1.z + a2.z + a3.z;
  float rw = a0.w + a1.w + a2.w + a3.w;
  atomicAdd(&out[col + 0], rx);
  atomicAdd(&out[col + 1], ry);
  atomicAdd(&out[col + 2], rz);
  atomicAdd(&out[col + 3], rw);
}

extern "C" void kernel_launch(void* const* d_in, const int* in_sizes, int n_in,
                              void* d_out, int out_size, void* d_ws, size_t ws_size,
                              hipStream_t stream) {
  const float* x  = (const float*)d_in[0];
  const int*   ei = (const int*)d_in[1];
  const float* W1 = (const float*)d_in[2];
  const float* b1 = (const float*)d_in[3];
  const float* Wr = (const float*)d_in[4];
  const float* br = (const float*)d_in[5];
  float* out = (float*)d_out;

  // ws layout (fp32/int32): deg[4096] t[4096] nnz[16] nzk[32768] nzv[32768]
  float* deg = (float*)d_ws;
  float* t   = deg + N_NODES;
  int*   nnz = (int*)(t + N_NODES);
  int*   nzk = nnz + 16;
  float* nzv = (float*)(nzk + K_TOT);

  k_init   <<<(N_NODES + 255) / 256, 256, 0, stream>>>(deg, t, out, br, nnz);
  k_deg    <<<(N_EDGES + 255) / 256, 256, 0, stream>>>(ei, deg);
  k_scatter<<<(N_EDGES + 255) / 256, 256, 0, stream>>>(ei, x, deg, t);
  k_hc     <<<(N_NODES + 255) / 256, 256, 0, stream>>>(x, deg, t, W1, b1, nnz, nzk, nzv);
  k_gemv   <<<4 * NCHUNK, GEMV_BLOCK, 0, stream>>>(Wr, nnz, nzk, nzv, out);
}